// Round 1
// 293.976 us; speedup vs baseline: 1.0592x; 1.0592x over previous
//
#include <hip/hip_runtime.h>
#include <hip/hip_bf16.h>
#include <math.h>

typedef __bf16 bf16;
typedef __bf16 bf16x2 __attribute__((ext_vector_type(2)));
typedef __bf16 bf16x4 __attribute__((ext_vector_type(4)));
typedef __bf16 bf16x8 __attribute__((ext_vector_type(8)));
typedef float  f32x4  __attribute__((ext_vector_type(4)));
typedef float  f32x16 __attribute__((ext_vector_type(16)));
typedef int    i32x2  __attribute__((ext_vector_type(2)));
typedef int    i32x4  __attribute__((ext_vector_type(4)));

#define SEQ 4096
#define DM  384
#define NH  6
#define DK  64
#define NB  2
#define WN  (DM * DM)
#define EPSLN 1e-6f

// dual-dtype scalar load: f32 ? float : bf16   (flag is a VALUE, wave-uniform)
__device__ __forceinline__ float ldT(const void* p, size_t i, int f32) {
    return f32 ? ((const float*)p)[i] : (float)(((const bf16*)p)[i]);
}

// ---------------------------------------------------------------------------
// z = LN(LN(x, ra, rb), a0, b0)  — torch style: unbiased std, /(std+eps)
// Round-16 scalar-load version (measured best; R17's paired loads were -4us).
// ---------------------------------------------------------------------------
__global__ __launch_bounds__(256) void ln2_kernel(
    const void* __restrict__ x, int xf32,
    const float* __restrict__ ra, const float* __restrict__ rb,
    const float* __restrict__ a0, const float* __restrict__ b0, bf16* __restrict__ z)
{
    int row  = blockIdx.x * 4 + (threadIdx.x >> 6);
    int lane = threadIdx.x & 63;
    size_t base = (size_t)row * DM;

    float v[6];
    float s = 0.f;
    #pragma unroll
    for (int i = 0; i < 6; i++) { v[i] = ldT(x, base + lane + i * 64, xf32); s += v[i]; }
    #pragma unroll
    for (int off = 1; off < 64; off <<= 1) s += __shfl_xor(s, off);
    float m = s * (1.f / DM);
    float sq = 0.f;
    #pragma unroll
    for (int i = 0; i < 6; i++) { float d = v[i] - m; sq += d * d; }
    #pragma unroll
    for (int off = 1; off < 64; off <<= 1) sq += __shfl_xor(sq, off);
    float inv = 1.f / (sqrtf(sq * (1.f / (DM - 1))) + EPSLN);

    s = 0.f;
    #pragma unroll
    for (int i = 0; i < 6; i++) {
        int c = lane + i * 64;
        v[i] = ra[c] * (v[i] - m) * inv + rb[c];
        s += v[i];
    }
    #pragma unroll
    for (int off = 1; off < 64; off <<= 1) s += __shfl_xor(s, off);
    m = s * (1.f / DM);
    sq = 0.f;
    #pragma unroll
    for (int i = 0; i < 6; i++) { float d = v[i] - m; sq += d * d; }
    #pragma unroll
    for (int off = 1; off < 64; off <<= 1) sq += __shfl_xor(sq, off);
    inv = 1.f / (sqrtf(sq * (1.f / (DM - 1))) + EPSLN);

    bf16* zr = z + base;
    #pragma unroll
    for (int i = 0; i < 6; i++) {
        int c = lane + i * 64;
        zr[c] = (bf16)(a0[c] * (v[i] - m) * inv + b0[c]);
    }
}

// ---------------------------------------------------------------------------
// qkv GEMM, LDS-staged, BM=128 BN=64 BK=64 (round-16 proven config).
// grid (64,6,3)=1152 = 4.5 blocks/CU. Weights f32, converted during staging.
// z=0->q, z=1->k, z=2->V^T [b][h][d][s]. Prefetch AFTER barrier B.
// ---------------------------------------------------------------------------
__global__ __launch_bounds__(256) void qkv_kernel(
    const bf16* __restrict__ A,
    const float* __restrict__ wq, const float* __restrict__ wk, const float* __restrict__ wv,
    const float* __restrict__ bq, const float* __restrict__ bk, const float* __restrict__ bv,
    bf16* __restrict__ qkout, bf16* __restrict__ vt)
{
    const int z = blockIdx.z;
    const float* W    = (z == 0) ? wq : (z == 1) ? wk : wv;
    const float* bias = (z == 0) ? bq : (z == 1) ? bk : bv;

    const int t = threadIdx.x;
    const int wave = t >> 6, lane = t & 63;
    const int l15 = lane & 15, quad = lane >> 4;
    const int wr = wave >> 1, wc = wave & 1;
    const int m0 = blockIdx.x * 128;
    const int n0 = blockIdx.y * 64;

    __shared__ __attribute__((aligned(16))) bf16 As[128][72];
    __shared__ __attribute__((aligned(16))) bf16 Bs[64][72];

    const int r0 = t >> 2;            // 0..63
    const int c0 = (t & 3) * 16;      // 0,16,32,48

    const bf16*  aptr0 = A + (size_t)(m0 + r0) * DM + c0;
    const bf16*  aptr1 = A + (size_t)(m0 + 64 + r0) * DM + c0;
    const float* bptr  = W + (size_t)(n0 + r0) * DM + c0;

    bf16x8 ra00 = *(const bf16x8*)(aptr0);
    bf16x8 ra01 = *(const bf16x8*)(aptr0 + 8);
    bf16x8 ra10 = *(const bf16x8*)(aptr1);
    bf16x8 ra11 = *(const bf16x8*)(aptr1 + 8);
    f32x4 wv0 = *(const f32x4*)(bptr);
    f32x4 wv1 = *(const f32x4*)(bptr + 4);
    f32x4 wv2 = *(const f32x4*)(bptr + 8);
    f32x4 wv3 = *(const f32x4*)(bptr + 12);

    f32x4 acc[4][2];
    #pragma unroll
    for (int mi = 0; mi < 4; mi++)
        #pragma unroll
        for (int ni = 0; ni < 2; ni++) acc[mi][ni] = (f32x4){0.f, 0.f, 0.f, 0.f};

    for (int kk = 0; kk < DM; kk += 64) {
        __syncthreads();   // barrier A (drains prev prefetch — hidden)
        *(bf16x8*)&As[r0][c0]          = ra00;
        *(bf16x8*)&As[r0][c0 + 8]      = ra01;
        *(bf16x8*)&As[64 + r0][c0]     = ra10;
        *(bf16x8*)&As[64 + r0][c0 + 8] = ra11;
        {
            bf16x8 b0v, b1v;
            #pragma unroll
            for (int j = 0; j < 4; j++) {
                b0v[j] = (bf16)wv0[j]; b0v[4 + j] = (bf16)wv1[j];
                b1v[j] = (bf16)wv2[j]; b1v[4 + j] = (bf16)wv3[j];
            }
            *(bf16x8*)&Bs[r0][c0]     = b0v;
            *(bf16x8*)&Bs[r0][c0 + 8] = b1v;
        }
        __syncthreads();   // barrier B
        if (kk + 64 < DM) {   // prefetch next K-tile, drains at next barrier A
            ra00 = *(const bf16x8*)(aptr0 + kk + 64);
            ra01 = *(const bf16x8*)(aptr0 + kk + 64 + 8);
            ra10 = *(const bf16x8*)(aptr1 + kk + 64);
            ra11 = *(const bf16x8*)(aptr1 + kk + 64 + 8);
            wv0 = *(const f32x4*)(bptr + kk + 64);
            wv1 = *(const f32x4*)(bptr + kk + 64 + 4);
            wv2 = *(const f32x4*)(bptr + kk + 64 + 8);
            wv3 = *(const f32x4*)(bptr + kk + 64 + 12);
        }

        #pragma unroll
        for (int kc = 0; kc < 64; kc += 32) {
            bf16x8 af[4], bf[2];
            #pragma unroll
            for (int mi = 0; mi < 4; mi++)
                af[mi] = *(const bf16x8*)&As[wr * 64 + mi * 16 + l15][kc + quad * 8];
            #pragma unroll
            for (int ni = 0; ni < 2; ni++)
                bf[ni] = *(const bf16x8*)&Bs[wc * 32 + ni * 16 + l15][kc + quad * 8];
            #pragma unroll
            for (int mi = 0; mi < 4; mi++)
                #pragma unroll
                for (int ni = 0; ni < 2; ni++)
                    acc[mi][ni] = __builtin_amdgcn_mfma_f32_16x16x32_bf16(af[mi], bf[ni], acc[mi][ni], 0, 0, 0);
        }
    }

    if (z < 2) {
        bf16* out = qkout + (size_t)z * ((size_t)NB * SEQ * DM);
        #pragma unroll
        for (int ni = 0; ni < 2; ni++) {
            int col = n0 + wc * 32 + ni * 16 + l15;
            float bb = bias[col];
            #pragma unroll
            for (int mi = 0; mi < 4; mi++) {
                #pragma unroll
                for (int r = 0; r < 4; r++) {
                    int row = m0 + wr * 64 + mi * 16 + quad * 4 + r;
                    out[(size_t)row * DM + col] = (bf16)(acc[mi][ni][r] + bb);
                }
            }
        }
    } else {
        #pragma unroll
        for (int ni = 0; ni < 2; ni++) {
            int col = n0 + wc * 32 + ni * 16 + l15;
            int h = col >> 6, d = col & 63;
            float bb = bias[col];
            #pragma unroll
            for (int mi = 0; mi < 4; mi++) {
                int row0 = m0 + wr * 64 + mi * 16 + quad * 4;
                int b = row0 >> 12, s0 = row0 & (SEQ - 1);
                bf16x4 ov;
                #pragma unroll
                for (int r = 0; r < 4; r++) ov[r] = (bf16)(acc[mi][ni][r] + bb);
                *(bf16x4*)(vt + (((size_t)b * NH + h) * DK + d) * SEQ + s0) = ov;
            }
        }
    }
}

// ---------------------------------------------------------------------------
// proj GEMM, BK=64, fused split reduce (round-15 proven, byte-identical).
// ---------------------------------------------------------------------------
__device__ __forceinline__ bf16x8 combineA(
    const bf16* __restrict__ o0, const bf16* __restrict__ o1,
    const float* __restrict__ lsum, int row, int kcol)
{
    int b = row >> 12, s = row & (SEQ - 1);
    int h = kcol >> 6;
    size_t lidx = ((size_t)b * NH + h) * SEQ + s;
    float inv = 1.f / (lsum[lidx] + lsum[(size_t)(NB * NH * SEQ) + lidx]);
    size_t idx = (size_t)row * DM + kcol;
    bf16x8 a = *(const bf16x8*)(o0 + idx);
    bf16x8 c = *(const bf16x8*)(o1 + idx);
    bf16x8 r;
    #pragma unroll
    for (int j = 0; j < 8; j++) r[j] = (bf16)(((float)a[j] + (float)c[j]) * inv);
    return r;
}

__global__ __launch_bounds__(256) void proj_kernel(
    const bf16* __restrict__ o0, const bf16* __restrict__ o1,
    const float* __restrict__ lsum,
    const float* __restrict__ wo, const float* __restrict__ bo,
    const void* __restrict__ xin, int f32in,
    void* __restrict__ xout, int f32out)
{
    const int t = threadIdx.x;
    const int wave = t >> 6, lane = t & 63;
    const int l15 = lane & 15, quad = lane >> 4;
    const int wr = wave >> 1, wc = wave & 1;
    const int m0 = blockIdx.x * 64;
    const int n0 = blockIdx.y * 64;

    __shared__ __attribute__((aligned(16))) bf16 As[64][72];
    __shared__ __attribute__((aligned(16))) bf16 Bs[64][72];

    const int r0 = t >> 2;
    const int c0 = (t & 3) * 16;
    const int arow = m0 + r0;
    const float* bptr = wo + (size_t)(n0 + r0) * DM + c0;

    bf16x8 ca0 = combineA(o0, o1, lsum, arow, c0);
    bf16x8 ca1 = combineA(o0, o1, lsum, arow, c0 + 8);
    f32x4 wv0 = *(const f32x4*)(bptr);
    f32x4 wv1 = *(const f32x4*)(bptr + 4);
    f32x4 wv2 = *(const f32x4*)(bptr + 8);
    f32x4 wv3 = *(const f32x4*)(bptr + 12);

    f32x4 acc[2][2];
    #pragma unroll
    for (int mi = 0; mi < 2; mi++)
        #pragma unroll
        for (int ni = 0; ni < 2; ni++) acc[mi][ni] = (f32x4){0.f, 0.f, 0.f, 0.f};

    for (int kk = 0; kk < DM; kk += 64) {
        __syncthreads();
        *(bf16x8*)&As[r0][c0]     = ca0;
        *(bf16x8*)&As[r0][c0 + 8] = ca1;
        {
            bf16x8 b0v, b1v;
            #pragma unroll
            for (int j = 0; j < 4; j++) {
                b0v[j] = (bf16)wv0[j]; b0v[4 + j] = (bf16)wv1[j];
                b1v[j] = (bf16)wv2[j]; b1v[4 + j] = (bf16)wv3[j];
            }
            *(bf16x8*)&Bs[r0][c0]     = b0v;
            *(bf16x8*)&Bs[r0][c0 + 8] = b1v;
        }
        __syncthreads();
        if (kk + 64 < DM) {
            ca0 = combineA(o0, o1, lsum, arow, kk + 64 + c0);
            ca1 = combineA(o0, o1, lsum, arow, kk + 64 + c0 + 8);
            wv0 = *(const f32x4*)(bptr + kk + 64);
            wv1 = *(const f32x4*)(bptr + kk + 64 + 4);
            wv2 = *(const f32x4*)(bptr + kk + 64 + 8);
            wv3 = *(const f32x4*)(bptr + kk + 64 + 12);
        }

        #pragma unroll
        for (int kc = 0; kc < 64; kc += 32) {
            bf16x8 af[2], bf[2];
            #pragma unroll
            for (int mi = 0; mi < 2; mi++)
                af[mi] = *(const bf16x8*)&As[wr * 32 + mi * 16 + l15][kc + quad * 8];
            #pragma unroll
            for (int ni = 0; ni < 2; ni++)
                bf[ni] = *(const bf16x8*)&Bs[wc * 32 + ni * 16 + l15][kc + quad * 8];
            #pragma unroll
            for (int mi = 0; mi < 2; mi++)
                #pragma unroll
                for (int ni = 0; ni < 2; ni++)
                    acc[mi][ni] = __builtin_amdgcn_mfma_f32_16x16x32_bf16(af[mi], bf[ni], acc[mi][ni], 0, 0, 0);
        }
    }

    #pragma unroll
    for (int ni = 0; ni < 2; ni++) {
        int col = n0 + wc * 32 + ni * 16 + l15;
        float bb = bo[col];
        #pragma unroll
        for (int mi = 0; mi < 2; mi++) {
            #pragma unroll
            for (int r = 0; r < 4; r++) {
                size_t idx = (size_t)(m0 + wr * 32 + mi * 16 + quad * 4 + r) * DM + col;
                float val = ldT(xin, idx, f32in) + acc[mi][ni][r] + bb;
                if (f32out) ((float*)xout)[idx] = val;
                else        ((bf16*)xout)[idx] = (bf16)val;
            }
        }
    }
}

// ---------------------------------------------------------------------------
// Flash attention — rewritten around mfma_f32_32x32x16_bf16 with swapped QK^T
// (T12): P never touches LDS. Per wave: 32 q rows (col = lane&31 of the 32x32
// D-tile), Q in registers. K tile [128][72] LDS; V as 4 kv-subtiles with
// 40-el row stride + 16-el tile pad — every 8-lane service group of every
// LDS access covers 32 distinct banks (conflict-free by construction).
// PV B-frags built in-register: bf16-pack pairs + permlane32_swap (one swap
// fills dw0+dw2 of the fragment). Deferred softmax normalization via lsum.
// ---------------------------------------------------------------------------
__device__ __forceinline__ unsigned packbf(float lo, float hi) {
    bf16x2 t;
    t[0] = (bf16)lo;
    t[1] = (bf16)hi;
    return __builtin_bit_cast(unsigned, t);
}

// swap hi-half-lanes of a with lo-half-lanes of b.
// returns r[0]=a' (lanes<32: a, lanes>=32: b from lane-32),
//         r[1]=b' (lanes<32: a from lane+32, lanes>=32: b)
__device__ __forceinline__ i32x2 halfswap(unsigned a, unsigned b) {
#if defined(__has_builtin) && __has_builtin(__builtin_amdgcn_permlane32_swap)
    return __builtin_amdgcn_permlane32_swap((int)a, (int)b, false, false);
#else
    int pa = __shfl_xor((int)a, 32);
    int pb = __shfl_xor((int)b, 32);
    bool hi = (threadIdx.x & 32) != 0;
    i32x2 r;
    r[0] = hi ? pb : (int)a;
    r[1] = hi ? (int)b : pa;
    return r;
#endif
}

#define V_RS 40     // V subtile row stride (elements): 20 dwords -> 8-lane groups spread
#define V_TS 2576   // V subtile stride (elements): 1288 dwords = 8 mod 32

__global__ __launch_bounds__(256, 3) void attn_kernel(
    const bf16* __restrict__ q, const bf16* __restrict__ k, const bf16* __restrict__ vt,
    bf16* __restrict__ o0, bf16* __restrict__ o1, float* __restrict__ lsum)
{
    int qt = blockIdx.x, h = blockIdx.y;
    int b = blockIdx.z >> 1, split = blockIdx.z & 1;
    const int t = threadIdx.x;
    const int wave = t >> 6, lane = t & 63;
    const int L = lane & 31, hf = lane >> 5;
    const int q0 = qt * 128;
    const int kvbase = split * (SEQ / 2);
    size_t basebh = (size_t)b * SEQ * DM + (size_t)h * DK;

    __shared__ __attribute__((aligned(16))) bf16 Ks[128][72];
    __shared__ __attribute__((aligned(16))) bf16 VtL[4 * V_TS];

    // Q fragments (B operand of 32x32x16): n = L (q row), k(d) = 16*ks + 8*hf + j
    const int qrow = q0 + wave * 32 + L;
    const bf16* qp = q + basebh + (size_t)qrow * DM + 8 * hf;
    bf16x8 aq[4];
    #pragma unroll
    for (int ks = 0; ks < 4; ks++) aq[ks] = *(const bf16x8*)(qp + 16 * ks);

    const float c2 = 0.18033688011112042f;   // log2(e)/8
    float lrA = 0.f, lrB = 0.f;
    f32x16 oacc[2];
    #pragma unroll
    for (int db = 0; db < 2; db++)
        #pragma unroll
        for (int r = 0; r < 16; r++) oacc[db][r] = 0.f;

    // staging (global access pattern identical to proven kernel)
    const int sd  = t >> 2;             // V: d row 0..63
    const int sc  = t & 3;              // V: kv chunk 0..3
    const bf16* vtrow0 = vt + (((size_t)b * NH + h) * DK + sd) * SEQ + sc * 32;
    const int skk = t >> 1;             // K: kv row 0..127
    const int sdk = (t & 1) * 32;       // K: d cols
    const bf16* krow0 = k + basebh + (size_t)skk * DM + sdk;

    bf16x8 vr0 = *(const bf16x8*)(vtrow0 + kvbase);
    bf16x8 vr1 = *(const bf16x8*)(vtrow0 + kvbase + 8);
    bf16x8 vr2 = *(const bf16x8*)(vtrow0 + kvbase + 16);
    bf16x8 vr3 = *(const bf16x8*)(vtrow0 + kvbase + 24);
    bf16x8 kr0 = *(const bf16x8*)(krow0 + (size_t)kvbase * DM);
    bf16x8 kr1 = *(const bf16x8*)(krow0 + (size_t)kvbase * DM + 8);
    bf16x8 kr2 = *(const bf16x8*)(krow0 + (size_t)kvbase * DM + 16);
    bf16x8 kr3 = *(const bf16x8*)(krow0 + (size_t)kvbase * DM + 24);

    for (int it = 0; it < 16; it++) {
        __syncthreads();   // barrier A (prev tile's reads done)
        {
            bf16* vw = &VtL[sc * V_TS + sd * V_RS];
            *(bf16x8*)(vw)      = vr0;
            *(bf16x8*)(vw + 8)  = vr1;
            *(bf16x8*)(vw + 16) = vr2;
            *(bf16x8*)(vw + 24) = vr3;
            *(bf16x8*)&Ks[skk][sdk]      = kr0;
            *(bf16x8*)&Ks[skk][sdk + 8]  = kr1;
            *(bf16x8*)&Ks[skk][sdk + 16] = kr2;
            *(bf16x8*)&Ks[skk][sdk + 24] = kr3;
        }
        __syncthreads();   // barrier B

        {   // prefetch next tile: drains at next barrier A
            int kvn = (it + 1 < 16) ? kvbase + (it + 1) * 128 : kvbase;
            const bf16* vp = vtrow0 + kvn;
            vr0 = *(const bf16x8*)(vp);
            vr1 = *(const bf16x8*)(vp + 8);
            vr2 = *(const bf16x8*)(vp + 16);
            vr3 = *(const bf16x8*)(vp + 24);
            const bf16* kp2 = krow0 + (size_t)kvn * DM;
            kr0 = *(const bf16x8*)(kp2);
            kr1 = *(const bf16x8*)(kp2 + 8);
            kr2 = *(const bf16x8*)(kp2 + 16);
            kr3 = *(const bf16x8*)(kp2 + 24);
        }

        #pragma unroll
        for (int kvb = 0; kvb < 4; kvb++) {
            // --- QK^T (swapped): D[kv][q], col = q = L, row = kv = (reg&3)+8*(reg>>2)+4*hf
            f32x16 sacc;
            #pragma unroll
            for (int r = 0; r < 16; r++) sacc[r] = 0.f;
            #pragma unroll
            for (int ks = 0; ks < 4; ks++) {
                bf16x8 kf = *(const bf16x8*)&Ks[kvb * 32 + L][ks * 16 + hf * 8];
                sacc = __builtin_amdgcn_mfma_f32_32x32x16_bf16(kf, aq[ks], sacc, 0, 0, 0);
            }

            // --- exp + running row-sum (normalization deferred to proj)
            float p[16];
            #pragma unroll
            for (int r = 0; r < 16; r++) {
                p[r] = __builtin_amdgcn_exp2f(sacc[r] * c2);
                if (r & 1) lrB += p[r]; else lrA += p[r];
            }

            // --- pack pairs along kv; R indexes kv-octet (reg>>2)
            unsigned pk0[4], pk1[4];
            #pragma unroll
            for (int R = 0; R < 4; R++) {
                pk0[R] = packbf(p[4 * R], p[4 * R + 1]);
                pk1[R] = packbf(p[4 * R + 2], p[4 * R + 3]);
            }

            // --- build PV B-frags in-register (2 frags of k=16 per kv-block)
            #pragma unroll
            for (int c2i = 0; c2i < 2; c2i++) {
                i32x2 r0 = halfswap(pk0[2 * c2i], pk0[2 * c2i + 1]);
                i32x2 r1 = halfswap(pk1[2 * c2i], pk1[2 * c2i + 1]);
                i32x4 w;
                w[0] = r0[0]; w[1] = r1[0]; w[2] = r0[1]; w[3] = r1[1];
                bf16x8 pb = __builtin_bit_cast(bf16x8, w);
                #pragma unroll
                for (int db = 0; db < 2; db++) {
                    bf16x8 av = *(const bf16x8*)&VtL[kvb * V_TS + (db * 32 + L) * V_RS
                                                     + c2i * 16 + hf * 8];
                    oacc[db] = __builtin_amdgcn_mfma_f32_32x32x16_bf16(av, pb, oacc[db], 0, 0, 0);
                }
            }
        }
    }

    // epilogue: unscaled O~ + lsum (proj divides by the combined sum)
    bf16* osel = split ? o1 : o0;
    float lrow = lrA + lrB;
    lrow += __shfl_xor(lrow, 32);
    bf16* op = osel + basebh + (size_t)qrow * DM;
    #pragma unroll
    for (int db = 0; db < 2; db++) {
        #pragma unroll
        for (int R = 0; R < 4; R++) {
            bf16x4 ov;
            #pragma unroll
            for (int r = 0; r < 4; r++) ov[r] = (bf16)oacc[db][4 * R + r];
            *(bf16x4*)(op + db * 32 + R * 8 + hf * 4) = ov;
        }
    }
    if (hf == 0)
        lsum[(size_t)split * (NB * NH * SEQ) + ((size_t)b * NH + h) * SEQ + qrow] = lrow;
}

// ---------------------------------------------------------------------------
extern "C" void kernel_launch(void* const* d_in, const int* in_sizes, int n_in,
                              void* d_out, int out_size, void* d_ws, size_t ws_size,
                              hipStream_t stream) {
    const size_t SZ = (size_t)NB * SEQ * DM;

    const float* x   = (const float*)d_in[0];
    const float* a0  = (const float*)d_in[1];
    const float* b0  = (const float*)d_in[2];
    const float* ra0 = (const float*)d_in[3];
    const float* rb0 = (const float*)d_in[4];
    const float* ra1 = (const float*)d_in[5];
    const float* rb1 = (const float*)d_in[6];
    const float* wq  = (const float*)d_in[7];  const float* bq = (const float*)d_in[8];
    const float* wk  = (const float*)d_in[9];  const float* bk = (const float*)d_in[10];
    const float* wv  = (const float*)d_in[11]; const float* bv = (const float*)d_in[12];
    const float* wo  = (const float*)d_in[13]; const float* bo = (const float*)d_in[14];

    bf16* zob = (bf16*)d_ws;     // z, then attn O~ split-0
    bf16* qb  = zob + SZ;
    bf16* kb  = qb + SZ;
    bf16* vtb = kb + SZ;         // V^T [NB][NH][DK][SEQ]
    bf16* x1  = vtb + SZ;
    bf16* o1b = x1 + SZ;         // attn O~ split-1
    float* lsum = (float*)(o1b + SZ);  // [2][NB][NH][SEQ] f32

    dim3 gLN(NB * SEQ / 4);
    dim3 gG(NB * SEQ / 128, DM / 64, 3);
    dim3 gP(NB * SEQ / 64, DM / 64);
    dim3 gA(SEQ / 128, NH, NB * 2);

    // pass 1
    ln2_kernel<<<gLN, 256, 0, stream>>>(x, 1, ra0, rb0, a0, b0, zob);
    qkv_kernel<<<gG, 256, 0, stream>>>(zob, wq, wk, wv, bq, bk, bv, qb, vtb);
    attn_kernel<<<gA, 256, 0, stream>>>(qb, kb, vtb, zob, o1b, lsum);
    proj_kernel<<<gP, 256, 0, stream>>>(zob, o1b, lsum, wo, bo, x, 1, x1, 0);
    // pass 2
    ln2_kernel<<<gLN, 256, 0, stream>>>(x1, 0, ra1, rb1, a0, b0, zob);
    qkv_kernel<<<gG, 256, 0, stream>>>(zob, wq, wk, wv, bq, bk, bv, qb, vtb);
    attn_kernel<<<gA, 256, 0, stream>>>(qb, kb, vtb, zob, o1b, lsum);
    proj_kernel<<<gP, 256, 0, stream>>>(zob, o1b, lsum, wo, bo, x1, 0, d_out, 1);
}